// Round 1
// baseline (195.693 us; speedup 1.0000x reference)
//
#include <hip/hip_runtime.h>
#include <math.h>

#define BATCH 32
#define HW 16384
#define WIDTH 128
#define NLINES 1000
#define NCAND 4096

// Flat output offsets (float elements), in reference return order:
// lcmap (32,128,128), lcoff (32,2,128,128), lleng (32,128,128),
// angle (32,128,128), lines (32,1000,2,2), score (32,1000)
#define OFF_LCMAP 0
#define OFF_LCOFF (BATCH * HW)                       // 524288
#define OFF_LLENG (OFF_LCOFF + 2 * BATCH * HW)       // 1572864
#define OFF_ANGLE (OFF_LLENG + BATCH * HW)           // 2097152
#define OFF_LINES (OFF_ANGLE + BATCH * HW)           // 2621440
#define OFF_SCORE (OFF_LINES + BATCH * NLINES * 4)   // 2749440

__device__ __forceinline__ float sigmoidf_(float x) {
    return 1.0f / (1.0f + expf(-x));
}

// Elementwise: softmax over channels 0:2 (keep ch1), sigmoid transforms.
__global__ void prep_kernel(const float* __restrict__ in, float* __restrict__ out) {
    int tid = blockIdx.x * blockDim.x + threadIdx.x;
    if (tid >= BATCH * HW) return;
    int b = tid >> 14;          // / 16384
    int p = tid & (HW - 1);
    const float* ib = in + (size_t)b * 6 * HW;
    float x0 = ib[p];
    float x1 = ib[HW + p];
    float x2 = ib[2 * HW + p];
    float x3 = ib[3 * HW + p];
    float x4 = ib[4 * HW + p];
    float x5 = ib[5 * HW + p];
    // softmax([x0,x1])[1], computed as JAX does (subtract max, exp, normalize)
    float m = fmaxf(x0, x1);
    float e0 = expf(x0 - m);
    float e1 = expf(x1 - m);
    out[OFF_LCMAP + tid] = e1 / (e0 + e1);
    out[OFF_LCOFF + b * 2 * HW + p]      = sigmoidf_(x2) - 0.5f;
    out[OFF_LCOFF + b * 2 * HW + HW + p] = sigmoidf_(x3) - 0.5f;
    out[OFF_LLENG + tid] = sigmoidf_(x4);
    out[OFF_ANGLE + tid] = sigmoidf_(x5);
}

// keep iff v >= all in-bounds 3x3 neighbors (matches h == maxpool3x3(h) with -inf pad)
__device__ __forceinline__ bool is_keep(const float* __restrict__ L, int p) {
    int y = p >> 7, x = p & (WIDTH - 1);
    float v = L[p];
    #pragma unroll
    for (int dy = -1; dy <= 1; ++dy) {
        int yy = y + dy;
        if (yy < 0 || yy > WIDTH - 1) continue;
        #pragma unroll
        for (int dx = -1; dx <= 1; ++dx) {
            if (dy == 0 && dx == 0) continue;
            int xx = x + dx;
            if (xx < 0 || xx > WIDTH - 1) continue;
            if (L[yy * WIDTH + xx] > v) return false;
        }
    }
    return true;
}

// One block (1024 threads) per batch: NMS candidate collection -> bitonic
// top-1000 (stable-tie replication of lax.top_k) -> line endpoints ->
// structure NMS on scores.
__global__ __launch_bounds__(1024) void lines_kernel(float* __restrict__ out) {
    __shared__ unsigned long long keys[NCAND];   // 32 KB
    __shared__ float ls[NLINES * 4];             // 16 KB  (p1y,p1x,p2y,p2x)
    __shared__ float ss[NLINES];                 //  4 KB
    __shared__ int cnt;

    const int b = blockIdx.x;
    const int tid = threadIdx.x;
    const float* __restrict__ L = out + OFF_LCMAP + b * HW;

    if (tid == 0) cnt = 0;
    for (int i = tid; i < NCAND; i += 1024) keys[i] = 0ULL;
    __syncthreads();

    // Collect local maxima as packed keys: (value_bits << 32) | (~idx).
    // Values are softmax outputs (>0), so uint bit order == float order.
    // Inverted index -> on equal value, smaller index sorts first (stable top_k).
    for (int p = tid; p < HW; p += 1024) {
        float v = L[p];
        if (is_keep(L, p)) {
            int pos = atomicAdd(&cnt, 1);
            if (pos < NCAND) {
                keys[pos] = ((unsigned long long)__float_as_uint(v) << 32)
                          | (unsigned long long)(0xFFFFFFFFu - (unsigned)p);
            }
        }
    }
    __syncthreads();

    // Bitonic sort, descending (unique keys -> total order).
    for (int size = 2; size <= NCAND; size <<= 1) {
        for (int stride = size >> 1; stride > 0; stride >>= 1) {
            for (int idx = tid; idx < NCAND; idx += 1024) {
                int partner = idx ^ stride;
                if (partner > idx) {
                    bool up = ((idx & size) != 0);
                    unsigned long long a = keys[idx];
                    unsigned long long c = keys[partner];
                    if ((a > c) == up) { keys[idx] = c; keys[partner] = a; }
                }
            }
            __syncthreads();
        }
    }

    // Fallback (never triggers for this data): if fewer than NLINES local
    // maxima, top_k returns zeros at the lowest non-kept flat indices.
    if (tid == 0 && cnt < NLINES) {
        int c = cnt < NCAND ? cnt : NCAND;
        int need = NLINES - c;
        int filled = 0;
        for (int p = 0; p < HW && filled < need; ++p) {
            if (!is_keep(L, p)) {
                keys[c + filled] = (unsigned long long)(0xFFFFFFFFu - (unsigned)p);
                ++filled;
            }
        }
    }
    __syncthreads();

    // Line endpoints for the top NLINES.
    const float* __restrict__ off0 = out + OFF_LCOFF + b * 2 * HW;
    const float* __restrict__ off1 = off0 + HW;
    const float* __restrict__ leng = out + OFF_LLENG + b * HW;
    const float* __restrict__ ang  = out + OFF_ANGLE + b * HW;
    for (int k = tid; k < NLINES; k += 1024) {
        unsigned long long key = keys[k];
        unsigned p = 0xFFFFFFFFu - (unsigned)(key & 0xFFFFFFFFull);
        float score = __uint_as_float((unsigned)(key >> 32));
        int yi = p >> 7, xi = p & (WIDTH - 1);
        float yc = (float)yi + off0[p] + 0.5f;
        float xc = (float)xi + off1[p] + 0.5f;
        float half_len = leng[p] * 64.0f;            // RESOLUTION/2
        float th = ang[p] * 3.14159265358979323846f; // rounds to f32 pi
        float dy = half_len * sinf(th);
        float dx = half_len * cosf(th);
        float p1y = yc - dy, p1x = xc - dx;
        float p2y = yc + dy, p2x = xc + dx;
        float* lo = out + OFF_LINES + (size_t)(b * NLINES + k) * 4;
        lo[0] = p1y; lo[1] = p1x; lo[2] = p2y; lo[3] = p2x;
        ls[k * 4 + 0] = p1y; ls[k * 4 + 1] = p1x;
        ls[k * 4 + 2] = p2y; ls[k * 4 + 3] = p2x;
        ss[k] = score;
    }
    __syncthreads();

    // Structure NMS: suppress k if any i<k has min-pairing sq-dist <= 2.0.
    for (int k = tid; k < NLINES; k += 1024) {
        float p1y = ls[k * 4 + 0], p1x = ls[k * 4 + 1];
        float p2y = ls[k * 4 + 2], p2x = ls[k * 4 + 3];
        bool sup = false;
        for (int i = 0; i < k; ++i) {
            float q1y = ls[i * 4 + 0], q1x = ls[i * 4 + 1];
            float q2y = ls[i * 4 + 2], q2x = ls[i * 4 + 3];
            float d1 = (q1y - p1y) * (q1y - p1y) + (q1x - p1x) * (q1x - p1x)
                     + (q2y - p2y) * (q2y - p2y) + (q2x - p2x) * (q2x - p2x);
            float d2 = (q1y - p2y) * (q1y - p2y) + (q1x - p2x) * (q1x - p2x)
                     + (q2y - p1y) * (q2y - p1y) + (q2x - p1x) * (q2x - p1x);
            float dist = fminf(d1, d2);
            if (dist <= 2.0f) { sup = true; break; }
        }
        out[OFF_SCORE + b * NLINES + k] = sup ? 0.0f : ss[k];
    }
}

extern "C" void kernel_launch(void* const* d_in, const int* in_sizes, int n_in,
                              void* d_out, int out_size, void* d_ws, size_t ws_size,
                              hipStream_t stream) {
    const float* in = (const float*)d_in[0];
    float* out = (float*)d_out;
    (void)in_sizes; (void)n_in; (void)out_size; (void)d_ws; (void)ws_size;

    prep_kernel<<<(BATCH * HW + 255) / 256, 256, 0, stream>>>(in, out);
    lines_kernel<<<BATCH, 1024, 0, stream>>>(out);
}